// Round 6
// baseline (2689.611 us; speedup 1.0000x reference)
//
#include <hip/hip_runtime.h>
#include <math.h>

// Problem constants
#define B 128
#define T 256
#define D 512
#define H 1024
#define KTOT 1536   // D + H
#define N4 4096     // 4*H

typedef short short8 __attribute__((ext_vector_type(8)));
typedef float f32x16 __attribute__((ext_vector_type(16)));

__device__ __forceinline__ unsigned short f2bf(float f) {
    unsigned int u = __builtin_bit_cast(unsigned int, f);
    unsigned int r = (u + 0x7fffu + ((u >> 16) & 1u)) >> 16;  // RNE
    return (unsigned short)r;
}
__device__ __forceinline__ float bf2f(unsigned short s) {
    unsigned int u = ((unsigned int)s) << 16;
    return __builtin_bit_cast(float, u);
}
__device__ __forceinline__ float sigm(float x) { return 1.f / (1.f + __expf(-x)); }
__device__ __forceinline__ float tanh_fast(float x) {
    return 1.f - 2.f / (1.f + __expf(2.f * x));
}

// x fp32 [B][T][D] -> xb bf16 [T][B][D]
__global__ __launch_bounds__(256) void convert_x(
    const float* __restrict__ x, unsigned short* __restrict__ xb)
{
    int bid = blockIdx.x;          // t*B + b
    int t = bid >> 7;
    int b = bid & 127;
    int d = threadIdx.x * 2;
    const float2 v = *(const float2*)&x[((size_t)b * T + t) * D + d];
    unsigned int packed = (unsigned int)f2bf(v.x) | ((unsigned int)f2bf(v.y) << 16);
    *(unsigned int*)&xb[((size_t)t * B + b) * D + d] = packed;
}

// Wk fp32 [KTOT][4H] -> Wp bf16 [4096][KTOT], permuted: pcol = hc*4 + g
__global__ __launch_bounds__(256) void convert_W(
    const float* __restrict__ Wk, unsigned short* __restrict__ Wp)
{
    __shared__ float tile[32][33];
    int nb = blockIdx.x;   // 0..127
    int kb = blockIdx.y;   // 0..47
    int tx = threadIdx.x & 31;
    int ty = threadIdx.x >> 5;   // 0..7
    #pragma unroll
    for (int i = 0; i < 4; ++i) {
        int k = kb * 32 + ty + i * 8;
        tile[ty + i * 8][tx] = Wk[(size_t)k * N4 + nb * 32 + tx];
    }
    __syncthreads();
    #pragma unroll
    for (int i = 0; i < 4; ++i) {
        int n = nb * 32 + ty + i * 8;
        int pcol = ((n & 1023) << 2) | (n >> 10);
        Wp[(size_t)pcol * KTOT + kb * 32 + tx] = f2bf(tile[tx][ty + i * 8]);
    }
}

// ============================================================================
// BIG-WS PATH: per-step h buffers hseq[T][B][H]. Producers write h via
// agent-scope (LLC write-through) stores; consumers read with PLAIN CACHED
// dwordx4 loads — safe because each h_t address is written exactly once per
// dispatch and only demand-filled into L1/L2 after the flag (no stale lines
// possible; dispatch boundaries writeback+invalidate L2 across kernels).
// Flags: one store per producer block + per-lane poll by wave 0 (no RMW).
// ============================================================================
__global__ __launch_bounds__(256, 1) void lstm_persist_big(
    const unsigned short* __restrict__ xb,   // [T][B][D] bf16
    const unsigned short* __restrict__ Wp,   // [4096][KTOT] bf16 permuted
    const float* __restrict__ bk,            // [4H]
    unsigned short* __restrict__ hseq,       // [T][B][H] bf16
    unsigned int* __restrict__ flg)          // [T][4][64] flags (zeroed)
{
    __shared__ __align__(16) char smem[65536];
    float (*zbuf)[64][36] = (float (*)[64][36])smem;                     // 18432 B
    unsigned short (*hbuf)[20] = (unsigned short (*)[20])(smem + 18432); // 1280 B

    const int tid  = threadIdx.x;
    const int bi   = blockIdx.x;
    const int rg   = bi >> 6;      // rows [32rg, +32)
    const int cg   = bi & 63;      // h-cols [16cg, +16) = pcols [64cg, +64)
    const int w    = tid >> 6;
    const int lane = tid & 63;
    const int ch   = w & 1;        // col-half
    const int kh   = w >> 1;       // K-half
    const int l31  = lane & 31;
    const int lhi  = lane >> 5;    // 0/1

    const int row = rg * 32 + l31;             // A row (m = lane&31)
    const int pc  = cg * 64 + ch * 32 + l31;   // B pcol (n = lane&31)

    // ---- W fragments into registers, forever ----
    short8 wb[48];
    const unsigned short* wbase = Wp + (size_t)pc * KTOT + lhi * 8;
    #pragma unroll
    for (int c = 0; c < 48; ++c)
        wb[c] = *(const short8*)(wbase + (2 * c + kh) * 16);

    // ---- bias preload ----
    float bi_[2], bj_[2], bf_[2], bo_[2];
    #pragma unroll
    for (int u = 0; u < 2; ++u) {
        int e   = tid + u * 256;
        int hcl = e >> 5;
        int hcg = cg * 16 + hcl;
        bi_[u] = bk[hcg];
        bj_[u] = bk[H + hcg];
        bf_[u] = bk[2 * H + hcg] + 1.0f;
        bo_[u] = bk[3 * H + hcg];
    }
    float cs0 = 0.f, cs1 = 0.f;

    for (int t = 0; t < T; ++t) {
        f32x16 accA = {0.f,0.f,0.f,0.f,0.f,0.f,0.f,0.f,
                       0.f,0.f,0.f,0.f,0.f,0.f,0.f,0.f};
        f32x16 accB = accA;

        // ---- x-part (chunks 0..15): cached loads, no h dependency ----
        const unsigned short* xr = xb + ((size_t)t * B + row) * D + lhi * 8;
        #pragma unroll
        for (int c = 0; c < 16; c += 2) {
            short8 a0 = *(const short8*)(xr + (2 * c + kh) * 16);
            short8 a1 = *(const short8*)(xr + (2 * (c + 1) + kh) * 16);
            accA = __builtin_amdgcn_mfma_f32_32x32x16_bf16(a0, wb[c], accA, 0, 0, 0);
            accB = __builtin_amdgcn_mfma_f32_32x32x16_bf16(a1, wb[c + 1], accB, 0, 0, 0);
        }

        if (t > 0) {
            // ---- wave 0: per-lane poll of the 64 producer flags ----
            if (w == 0) {
                const unsigned int* f = flg + ((size_t)(t - 1) * 4 + rg) * 64 + lane;
                while (__hip_atomic_load(f, __ATOMIC_RELAXED,
                                         __HIP_MEMORY_SCOPE_AGENT) == 0u)
                    __builtin_amdgcn_s_sleep(1);
            }
            __syncthreads();
            asm volatile("" ::: "memory");

            // ---- stage h slab (32 rows x 1024 bf16 = 64 KB) via CACHED
            //      dwordx4 loads (L2-amplified), XOR-swizzled into LDS ----
            const uint4* hsrc =
                (const uint4*)(hseq + ((size_t)(t - 1) * B + rg * 32) * H);
            #pragma unroll
            for (int j = 0; j < 16; ++j) {
                uint4 v = hsrc[j * 256 + tid];
                int L  = j * 256 + tid;        // 16B-group linear index
                int r  = L >> 7;               // LDS row 0..31
                int g  = L & 127;              // group within row
                int gs = g ^ (r & 7);          // bank swizzle
                *(uint4*)(smem + r * 2048 + gs * 16) = v;
            }
            __syncthreads();

            // ---- h-part (chunks 16..47) from LDS ----
            #pragma unroll
            for (int c = 16; c < 48; c += 2) {
                int hc0 = (2 * c + kh) * 16 + lhi * 8 - 512;
                int hc1 = (2 * (c + 1) + kh) * 16 + lhi * 8 - 512;
                short8 a0 = *(const short8*)(smem + l31 * 2048 +
                                             (((hc0 >> 3) ^ (l31 & 7)) * 16));
                short8 a1 = *(const short8*)(smem + l31 * 2048 +
                                             (((hc1 >> 3) ^ (l31 & 7)) * 16));
                accA = __builtin_amdgcn_mfma_f32_32x32x16_bf16(a0, wb[c], accA, 0, 0, 0);
                accB = __builtin_amdgcn_mfma_f32_32x32x16_bf16(a1, wb[c + 1], accB, 0, 0, 0);
            }
            __syncthreads();   // htile dead before zbuf overwrites it
        }

        accA += accB;

        // ---- K-partials to LDS. C/D: col=lane&31, row=(reg&3)+8*(reg>>2)+4*lhi
        #pragma unroll
        for (int q = 0; q < 4; ++q) {
            float4 v = { accA[4 * q + 0], accA[4 * q + 1],
                         accA[4 * q + 2], accA[4 * q + 3] };
            *(float4*)&zbuf[kh][ch * 32 + l31][lhi * 4 + q * 8] = v;
        }
        __syncthreads();

        // ---- gates ----
        #pragma unroll
        for (int u = 0; u < 2; ++u) {
            int e   = tid + u * 256;
            int r   = e & 31;
            int hcl = e >> 5;
            int pcb = hcl * 4;
            float zi = zbuf[0][pcb + 0][r] + zbuf[1][pcb + 0][r] + bi_[u];
            float zj = zbuf[0][pcb + 1][r] + zbuf[1][pcb + 1][r] + bj_[u];
            float zf = zbuf[0][pcb + 2][r] + zbuf[1][pcb + 2][r] + bf_[u];
            float zo = zbuf[0][pcb + 3][r] + zbuf[1][pcb + 3][r] + bo_[u];
            float& cc = u ? cs1 : cs0;
            float cn = cc * sigm(zf) + sigm(zi) * tanh_fast(zj);
            cc = cn;
            float hn = sigm(zo) * tanh_fast(cn);
            hbuf[r][hcl] = f2bf(hn);
        }
        __syncthreads();

        // ---- h-store: agent-scope (LLC write-through), coalesced ----
        {
            int r  = tid >> 3;
            int cp = tid & 7;
            unsigned int v = *(const unsigned int*)&hbuf[r][cp * 2];
            unsigned int* hdst = (unsigned int*)hseq;
            __hip_atomic_store(
                &hdst[((size_t)t * B + rg * 32 + r) * 512 + cg * 8 + cp], v,
                __ATOMIC_RELAXED, __HIP_MEMORY_SCOPE_AGENT);
        }
        __syncthreads();   // drains vmcnt: stores at LLC before flag
        asm volatile("" ::: "memory");

        if (tid == 0)
            __hip_atomic_store(&flg[((size_t)t * 4 + rg) * 64 + cg], 1u,
                               __ATOMIC_RELAXED, __HIP_MEMORY_SCOPE_AGENT);
    }
}

// ============================================================================
// FALLBACK PATH (ws too small): round-5 kernel verbatim — LLC-direct loads,
// ping-pong h buffers, per-rg arrive counter.
// ============================================================================
__global__ __launch_bounds__(256, 1) void lstm_persist_llc(
    const unsigned short* __restrict__ xb,
    const unsigned short* __restrict__ Wp,
    const float* __restrict__ bk,
    unsigned short* __restrict__ h0,
    unsigned short* __restrict__ h1,
    unsigned int* __restrict__ arr)
{
    __shared__ __align__(16) char smem[65536];
    float (*zbuf)[64][36] = (float (*)[64][36])smem;
    unsigned short (*hbuf)[20] = (unsigned short (*)[20])(smem + 18432);

    const int tid  = threadIdx.x;
    const int bi   = blockIdx.x;
    const int rg   = bi >> 6;
    const int cg   = bi & 63;
    const int w    = tid >> 6;
    const int lane = tid & 63;
    const int ch   = w & 1;
    const int kh   = w >> 1;
    const int l31  = lane & 31;
    const int lhi  = lane >> 5;

    const int row = rg * 32 + l31;
    const int pc  = cg * 64 + ch * 32 + l31;

    short8 wb[48];
    const unsigned short* wbase = Wp + (size_t)pc * KTOT + lhi * 8;
    #pragma unroll
    for (int c = 0; c < 48; ++c)
        wb[c] = *(const short8*)(wbase + (2 * c + kh) * 16);

    float bi_[2], bj_[2], bf_[2], bo_[2];
    #pragma unroll
    for (int u = 0; u < 2; ++u) {
        int e   = tid + u * 256;
        int hcl = e >> 5;
        int hcg = cg * 16 + hcl;
        bi_[u] = bk[hcg];
        bj_[u] = bk[H + hcg];
        bf_[u] = bk[2 * H + hcg] + 1.0f;
        bo_[u] = bk[3 * H + hcg];
    }
    float cs0 = 0.f, cs1 = 0.f;

    unsigned int* const arrg = arr + rg * 256;
    const unsigned int* const h0slab = (const unsigned int*)(h0 + (size_t)rg * 32 * H);
    const unsigned int* const h1slab = (const unsigned int*)(h1 + (size_t)rg * 32 * H);

    for (int t = 0; t < T; ++t) {
        f32x16 accA = {0.f,0.f,0.f,0.f,0.f,0.f,0.f,0.f,
                       0.f,0.f,0.f,0.f,0.f,0.f,0.f,0.f};
        f32x16 accB = accA;

        const unsigned short* xr = xb + ((size_t)t * B + row) * D + lhi * 8;
        #pragma unroll
        for (int c = 0; c < 16; c += 2) {
            short8 a0 = *(const short8*)(xr + (2 * c + kh) * 16);
            short8 a1 = *(const short8*)(xr + (2 * (c + 1) + kh) * 16);
            accA = __builtin_amdgcn_mfma_f32_32x32x16_bf16(a0, wb[c], accA, 0, 0, 0);
            accB = __builtin_amdgcn_mfma_f32_32x32x16_bf16(a1, wb[c + 1], accB, 0, 0, 0);
        }

        if (t > 0) {
            if (tid == 0) {
                while (__hip_atomic_load(&arrg[t - 1], __ATOMIC_RELAXED,
                                         __HIP_MEMORY_SCOPE_AGENT) < 64u)
                    __builtin_amdgcn_s_sleep(2);
            }
            __syncthreads();
            asm volatile("" ::: "memory");

            const unsigned int* hsrc = (t & 1) ? h1slab : h0slab;
            #pragma unroll
            for (int ib = 0; ib < 4; ++ib) {
                unsigned int tmp[16];
                #pragma unroll
                for (int j = 0; j < 16; ++j)
                    tmp[j] = __hip_atomic_load(&hsrc[(ib * 16 + j) * 256 + tid],
                                               __ATOMIC_RELAXED,
                                               __HIP_MEMORY_SCOPE_AGENT);
                #pragma unroll
                for (int j = 0; j < 16; ++j) {
                    int K   = ib * 16 + j;
                    int r   = K >> 1;
                    int cu  = ((K & 1) << 8) + tid;
                    int grp = (cu >> 2) ^ (r & 7);
                    *(unsigned int*)(smem + r * 2048 + grp * 16 + (cu & 3) * 4) = tmp[j];
                }
            }
            __syncthreads();

            #pragma unroll
            for (int c = 16; c < 48; c += 2) {
                int hc0 = (2 * c + kh) * 16 + lhi * 8 - 512;
                int hc1 = (2 * (c + 1) + kh) * 16 + lhi * 8 - 512;
                short8 a0 = *(const short8*)(smem + l31 * 2048 +
                                             (((hc0 >> 3) ^ (l31 & 7)) * 16));
                short8 a1 = *(const short8*)(smem + l31 * 2048 +
                                             (((hc1 >> 3) ^ (l31 & 7)) * 16));
                accA = __builtin_amdgcn_mfma_f32_32x32x16_bf16(a0, wb[c], accA, 0, 0, 0);
                accB = __builtin_amdgcn_mfma_f32_32x32x16_bf16(a1, wb[c + 1], accB, 0, 0, 0);
            }
            __syncthreads();
        }

        accA += accB;

        #pragma unroll
        for (int q = 0; q < 4; ++q) {
            float4 v = { accA[4 * q + 0], accA[4 * q + 1],
                         accA[4 * q + 2], accA[4 * q + 3] };
            *(float4*)&zbuf[kh][ch * 32 + l31][lhi * 4 + q * 8] = v;
        }
        __syncthreads();

        #pragma unroll
        for (int u = 0; u < 2; ++u) {
            int e   = tid + u * 256;
            int r   = e & 31;
            int hcl = e >> 5;
            int pcb = hcl * 4;
            float zi = zbuf[0][pcb + 0][r] + zbuf[1][pcb + 0][r] + bi_[u];
            float zj = zbuf[0][pcb + 1][r] + zbuf[1][pcb + 1][r] + bj_[u];
            float zf = zbuf[0][pcb + 2][r] + zbuf[1][pcb + 2][r] + bf_[u];
            float zo = zbuf[0][pcb + 3][r] + zbuf[1][pcb + 3][r] + bo_[u];
            float& cc = u ? cs1 : cs0;
            float cn = cc * sigm(zf) + sigm(zi) * tanh_fast(zj);
            cc = cn;
            float hn = sigm(zo) * tanh_fast(cn);
            hbuf[r][hcl] = f2bf(hn);
        }
        __syncthreads();

        {
            int r  = tid >> 3;
            int cp = tid & 7;
            unsigned int v = *(const unsigned int*)&hbuf[r][cp * 2];
            unsigned int* hdst = (unsigned int*)((t & 1) ? h0 : h1);
            __hip_atomic_store(&hdst[(size_t)(rg * 32 + r) * 512 + cg * 8 + cp], v,
                               __ATOMIC_RELAXED, __HIP_MEMORY_SCOPE_AGENT);
        }
        __syncthreads();
        asm volatile("" ::: "memory");

        if (tid == 0)
            __hip_atomic_fetch_add(&arrg[t], 1u, __ATOMIC_RELAXED,
                                   __HIP_MEMORY_SCOPE_AGENT);
    }
}

// out[128][1000] = h(bf16)[128][1024] @ w[1024][1000] + b
__global__ __launch_bounds__(256) void proj_kernel(
    const unsigned short* __restrict__ hb, const float* __restrict__ w,
    const float* __restrict__ bias, float* __restrict__ out)
{
    int cidx = blockIdx.x * 256 + threadIdx.x;  // 0..1023
    int bg   = blockIdx.y;                      // 0..7 -> 16 rows each
    bool valid = cidx < 1000;
    float acc[16];
    #pragma unroll
    for (int i = 0; i < 16; ++i) acc[i] = 0.f;

    for (int k = 0; k < H; k += 4) {
        float w0 = 0.f, w1 = 0.f, w2 = 0.f, w3 = 0.f;
        if (valid) {
            w0 = w[(size_t)(k + 0) * 1000 + cidx];
            w1 = w[(size_t)(k + 1) * 1000 + cidx];
            w2 = w[(size_t)(k + 2) * 1000 + cidx];
            w3 = w[(size_t)(k + 3) * 1000 + cidx];
        }
        #pragma unroll
        for (int i = 0; i < 16; ++i) {
            ushort4 hv = *(const ushort4*)&hb[(size_t)(bg * 16 + i) * H + k];
            acc[i] += bf2f(hv.x) * w0 + bf2f(hv.y) * w1
                    + bf2f(hv.z) * w2 + bf2f(hv.w) * w3;
        }
    }
    if (valid) {
        #pragma unroll
        for (int i = 0; i < 16; ++i)
            out[(size_t)(bg * 16 + i) * 1000 + cidx] = acc[i] + bias[cidx];
    }
}

extern "C" void kernel_launch(void* const* d_in, const int* in_sizes, int n_in,
                              void* d_out, int out_size, void* d_ws, size_t ws_size,
                              hipStream_t stream) {
    const float* x  = (const float*)d_in[0];  // [B,T,D]
    const float* Wk = (const float*)d_in[1];  // [D+H, 4H]
    const float* bk = (const float*)d_in[2];  // [4H]
    const float* w  = (const float*)d_in[3];  // [H, C]
    const float* b  = (const float*)d_in[4];  // [C]
    float* out = (float*)d_out;               // [B, C]

    // common prefix
    char* p = (char*)d_ws;
    unsigned short* xb = (unsigned short*)p;  p += (size_t)B * T * D * 2;   // 33.55 MB
    unsigned short* Wp = (unsigned short*)p;  p += (size_t)N4 * KTOT * 2;   // 12.58 MB

    const size_t big_bytes = (size_t)B * T * D * 2 + (size_t)N4 * KTOT * 2
                           + (size_t)T * B * H * 2 + (size_t)T * 4 * 64 * 4;

    convert_x<<<dim3(T * B), dim3(256), 0, stream>>>(x, xb);
    convert_W<<<dim3(N4 / 32, KTOT / 32), dim3(256), 0, stream>>>(Wk, Wp);

    if (ws_size >= big_bytes) {
        unsigned short* hseq = (unsigned short*)p;  p += (size_t)T * B * H * 2; // 64 MB
        unsigned int*   fl   = (unsigned int*)p;    p += (size_t)T * 4 * 64 * 4;
        hipMemsetAsync(fl, 0, (size_t)T * 4 * 64 * 4, stream);
        lstm_persist_big<<<dim3(256), dim3(256), 0, stream>>>(xb, Wp, bk, hseq, fl);
        proj_kernel<<<dim3(4, 8), dim3(256), 0, stream>>>(
            hseq + (size_t)(T - 1) * B * H, w, b, out);
    } else {
        unsigned short* h0 = (unsigned short*)p;  p += (size_t)B * H * 2;
        unsigned short* h1 = (unsigned short*)p;  p += (size_t)B * H * 2;
        unsigned int*   ar = (unsigned int*)p;    p += 4 * 256 * 4;
        hipMemsetAsync(ar, 0, 4 * 256 * 4, stream);
        lstm_persist_llc<<<dim3(256), dim3(256), 0, stream>>>(xb, Wp, bk, h0, h1, ar);
        proj_kernel<<<dim3(4, 8), dim3(256), 0, stream>>>(h0, w, b, out);
    }
}

// Round 7
// 2277.476 us; speedup vs baseline: 1.1810x; 1.1810x over previous
//
#include <hip/hip_runtime.h>
#include <math.h>

// Problem constants
#define B 128
#define T 256
#define D 512
#define H 1024
#define KTOT 1536   // D + H
#define N4 4096     // 4*H

typedef short short8 __attribute__((ext_vector_type(8)));
typedef float f32x16 __attribute__((ext_vector_type(16)));

__device__ __forceinline__ unsigned short f2bf(float f) {
    unsigned int u = __builtin_bit_cast(unsigned int, f);
    unsigned int r = (u + 0x7fffu + ((u >> 16) & 1u)) >> 16;  // RNE
    return (unsigned short)r;
}
__device__ __forceinline__ float bf2f(unsigned short s) {
    unsigned int u = ((unsigned int)s) << 16;
    return __builtin_bit_cast(float, u);
}
__device__ __forceinline__ float sigm(float x) { return 1.f / (1.f + __expf(-x)); }
__device__ __forceinline__ float tanh_fast(float x) {
    return 1.f - 2.f / (1.f + __expf(2.f * x));
}

// x fp32 [B][T][D] -> xb bf16 [T][B][D].  2048 blocks x 16 slices each.
__global__ __launch_bounds__(256) void convert_x(
    const float* __restrict__ x, unsigned short* __restrict__ xb)
{
    int d = threadIdx.x * 2;
    #pragma unroll 4
    for (int i = 0; i < 16; ++i) {
        int s = blockIdx.x * 16 + i;   // t*B + b
        int t = s >> 7;
        int b = s & 127;
        const float2 v = *(const float2*)&x[((size_t)b * T + t) * D + d];
        unsigned int packed = (unsigned int)f2bf(v.x) | ((unsigned int)f2bf(v.y) << 16);
        *(unsigned int*)&xb[((size_t)t * B + b) * D + d] = packed;
    }
}

// Wk fp32 [KTOT][4H] -> Wp bf16 [4096][KTOT], permuted: pcol = hc*4 + g
__global__ __launch_bounds__(256) void convert_W(
    const float* __restrict__ Wk, unsigned short* __restrict__ Wp)
{
    __shared__ float tile[32][33];
    int nb = blockIdx.x;   // 0..127
    int kb = blockIdx.y;   // 0..47
    int tx = threadIdx.x & 31;
    int ty = threadIdx.x >> 5;   // 0..7
    #pragma unroll
    for (int i = 0; i < 4; ++i) {
        int k = kb * 32 + ty + i * 8;
        tile[ty + i * 8][tx] = Wk[(size_t)k * N4 + nb * 32 + tx];
    }
    __syncthreads();
    #pragma unroll
    for (int i = 0; i < 4; ++i) {
        int n = nb * 32 + ty + i * 8;
        int pcol = ((n & 1023) << 2) | (n >> 10);
        Wp[(size_t)pcol * KTOT + kb * 32 + tx] = f2bf(tile[tx][ty + i * 8]);
    }
}

// Persistent LSTM. 256 blocks x 256 threads, 1 block/CU, W in registers.
// h exchange via LLC (agent-scope) loads/stores — NO cache-maintenance ops.
// The 64-producer all-to-all is pipelined in 4 groups of 16 producers:
// poll group g -> stage its 16 KB -> MFMA group g while loading group g+1.
__global__ __launch_bounds__(256, 1) void lstm_persist(
    const unsigned short* __restrict__ xb,   // [T][B][D] bf16
    const unsigned short* __restrict__ Wp,   // [4096][KTOT] bf16 permuted
    const float* __restrict__ bk,            // [4H]
    unsigned short* __restrict__ h0,         // [B][H] bf16 ping (final h)
    unsigned short* __restrict__ h1,         // [B][H] bf16 pong
    unsigned int* __restrict__ flg)          // [T][4][64] flags (zeroed)
{
    // LDS union: htile (64 KB, swizzled h slab) overlaps zbuf+hbuf (post-MFMA)
    __shared__ __align__(16) char smem[65536];
    float (*zbuf)[64][36] = (float (*)[64][36])smem;                     // 18432 B
    unsigned short (*hbuf)[20] = (unsigned short (*)[20])(smem + 18432); // 1280 B

    const int tid  = threadIdx.x;
    const int bi   = blockIdx.x;
    const int rg   = bi >> 6;      // rows [32rg, +32)
    const int cg   = bi & 63;      // h-cols [16cg, +16) = pcols [64cg, +64)
    const int w    = tid >> 6;
    const int lane = tid & 63;
    const int ch   = w & 1;        // col-half
    const int kh   = w >> 1;       // K-half
    const int l31  = lane & 31;
    const int lhi  = lane >> 5;    // 0/1

    const int row = rg * 32 + l31;             // A row (m = lane&31)
    const int pc  = cg * 64 + ch * 32 + l31;   // B pcol (n = lane&31)

    // ---- W fragments into registers, forever ----
    // chunk c (0..47) -> k16-chunk g = 2c + kh; frag k = g*16 + lhi*8 + j
    short8 wb[48];
    const unsigned short* wbase = Wp + (size_t)pc * KTOT + lhi * 8;
    #pragma unroll
    for (int c = 0; c < 48; ++c)
        wb[c] = *(const short8*)(wbase + (2 * c + kh) * 16);

    // ---- bias preload ----
    float bi_[2], bj_[2], bf_[2], bo_[2];
    #pragma unroll
    for (int u = 0; u < 2; ++u) {
        int e   = tid + u * 256;
        int hcl = e >> 5;
        int hcg = cg * 16 + hcl;
        bi_[u] = bk[hcg];
        bj_[u] = bk[H + hcg];
        bf_[u] = bk[2 * H + hcg] + 1.0f;   // forget bias folded
        bo_[u] = bk[3 * H + hcg];
    }
    float cs0 = 0.f, cs1 = 0.f;   // cell state, persistent in registers

    const unsigned long long* const h0slab =
        (const unsigned long long*)(h0 + (size_t)rg * 32 * H);
    const unsigned long long* const h1slab =
        (const unsigned long long*)(h1 + (size_t)rg * 32 * H);

    for (int t = 0; t < T; ++t) {
        f32x16 accA = {0.f,0.f,0.f,0.f,0.f,0.f,0.f,0.f,
                       0.f,0.f,0.f,0.f,0.f,0.f,0.f,0.f};
        f32x16 accB = accA;

        // ---- x-part (chunks 0..15): cached loads, no h dependency;
        //      overlaps the producers' step-(t-1) tails ----
        const unsigned short* xr = xb + ((size_t)t * B + row) * D + lhi * 8;
        #pragma unroll
        for (int c = 0; c < 16; c += 2) {
            short8 a0 = *(const short8*)(xr + (2 * c + kh) * 16);
            short8 a1 = *(const short8*)(xr + (2 * (c + 1) + kh) * 16);
            accA = __builtin_amdgcn_mfma_f32_32x32x16_bf16(a0, wb[c], accA, 0, 0, 0);
            accB = __builtin_amdgcn_mfma_f32_32x32x16_bf16(a1, wb[c + 1], accB, 0, 0, 0);
        }

        if (t > 0) {
            const unsigned long long* hs = (t & 1) ? h1slab : h0slab;
            const unsigned int* fbase = flg + ((size_t)(t - 1) * 4 + rg) * 64;
            unsigned long long tmp[8];

            // ---- poll + stage group 0 (producers 0..15 = h-cols 0..255) ----
            if (w == 0 && lane < 16) {
                while (__hip_atomic_load(&fbase[lane], __ATOMIC_RELAXED,
                                         __HIP_MEMORY_SCOPE_AGENT) == 0u)
                    __builtin_amdgcn_s_sleep(1);
            }
            __syncthreads();
            asm volatile("" ::: "memory");
            #pragma unroll
            for (int j = 0; j < 8; ++j)   // LLC-direct b64, coalesced
                tmp[j] = __hip_atomic_load(&hs[(4 * j + w) * 256 + lane],
                                           __ATOMIC_RELAXED,
                                           __HIP_MEMORY_SCOPE_AGENT);
            #pragma unroll
            for (int j = 0; j < 8; ++j) {  // swizzled LDS write
                int r  = 4 * j + w;
                int gs = ((lane >> 1)) ^ (r & 7);
                *(unsigned long long*)(smem + r * 2048 + gs * 16 + (lane & 1) * 8)
                    = tmp[j];
            }

            // ---- pipelined groups: MFMA g while loading g+1 ----
            #pragma unroll
            for (int g = 0; g < 4; ++g) {
                if (g < 3 && w == 0 && lane < 16) {
                    const unsigned int* f = &fbase[16 * (g + 1) + lane];
                    while (__hip_atomic_load(f, __ATOMIC_RELAXED,
                                             __HIP_MEMORY_SCOPE_AGENT) == 0u)
                        __builtin_amdgcn_s_sleep(1);
                }
                __syncthreads();   // group-g LDS writes visible; poll g+1 done
                asm volatile("" ::: "memory");

                if (g < 3) {       // issue global loads for g+1 (overlap MFMA)
                    #pragma unroll
                    for (int j = 0; j < 8; ++j)
                        tmp[j] = __hip_atomic_load(
                            &hs[(4 * j + w) * 256 + 64 * (g + 1) + lane],
                            __ATOMIC_RELAXED, __HIP_MEMORY_SCOPE_AGENT);
                }

                // MFMA the 8 chunks of group g (c = 16+8g .. 23+8g)
                #pragma unroll
                for (int cc = 0; cc < 8; cc += 2) {
                    int c0  = 16 + 8 * g + cc;
                    int hc0 = (2 * c0 + kh) * 16 + lhi * 8 - 512;
                    int hc1 = (2 * (c0 + 1) + kh) * 16 + lhi * 8 - 512;
                    short8 a0 = *(const short8*)(smem + l31 * 2048 +
                                                 (((hc0 >> 3) ^ (l31 & 7)) * 16));
                    short8 a1 = *(const short8*)(smem + l31 * 2048 +
                                                 (((hc1 >> 3) ^ (l31 & 7)) * 16));
                    accA = __builtin_amdgcn_mfma_f32_32x32x16_bf16(a0, wb[c0], accA, 0, 0, 0);
                    accB = __builtin_amdgcn_mfma_f32_32x32x16_bf16(a1, wb[c0 + 1], accB, 0, 0, 0);
                }

                if (g < 3) {       // park g+1 into its (disjoint) LDS region
                    #pragma unroll
                    for (int j = 0; j < 8; ++j) {
                        int r  = 4 * j + w;
                        int gs = (32 * (g + 1) + (lane >> 1)) ^ (r & 7);
                        *(unsigned long long*)(smem + r * 2048 + gs * 16 +
                                               (lane & 1) * 8) = tmp[j];
                    }
                }
            }
            __syncthreads();   // htile dead before zbuf overwrites it
        }

        accA += accB;

        // ---- K-partials to LDS. C/D: col=lane&31, row=(reg&3)+8*(reg>>2)+4*lhi
        #pragma unroll
        for (int q = 0; q < 4; ++q) {
            float4 v = { accA[4 * q + 0], accA[4 * q + 1],
                         accA[4 * q + 2], accA[4 * q + 3] };
            *(float4*)&zbuf[kh][ch * 32 + l31][lhi * 4 + q * 8] = v;
        }
        __syncthreads();

        // ---- gates: 512 h-elems/block, 2 per thread; results to hbuf ----
        #pragma unroll
        for (int u = 0; u < 2; ++u) {
            int e   = tid + u * 256;
            int r   = e & 31;
            int hcl = e >> 5;
            int pcb = hcl * 4;
            float zi = zbuf[0][pcb + 0][r] + zbuf[1][pcb + 0][r] + bi_[u];
            float zj = zbuf[0][pcb + 1][r] + zbuf[1][pcb + 1][r] + bj_[u];
            float zf = zbuf[0][pcb + 2][r] + zbuf[1][pcb + 2][r] + bf_[u];
            float zo = zbuf[0][pcb + 3][r] + zbuf[1][pcb + 3][r] + bo_[u];
            float& cc = u ? cs1 : cs0;
            float cn = cc * sigm(zf) + sigm(zi) * tanh_fast(zj);
            cc = cn;
            float hn = sigm(zo) * tanh_fast(cn);
            hbuf[r][hcl] = f2bf(hn);
        }
        __syncthreads();

        // ---- coalesced h-store: 256 uint agent-scope (LLC) stores ----
        {
            int r  = tid >> 3;
            int cp = tid & 7;
            unsigned int v = *(const unsigned int*)&hbuf[r][cp * 2];
            unsigned int* hdst = (unsigned int*)((t & 1) ? h0 : h1);
            __hip_atomic_store(&hdst[(size_t)(rg * 32 + r) * 512 + cg * 8 + cp], v,
                               __ATOMIC_RELAXED, __HIP_MEMORY_SCOPE_AGENT);
        }
        __syncthreads();   // drains vmcnt: stores at LLC before flag
        asm volatile("" ::: "memory");

        if (tid == 0)
            __hip_atomic_store(&flg[((size_t)t * 4 + rg) * 64 + cg], 1u,
                               __ATOMIC_RELAXED, __HIP_MEMORY_SCOPE_AGENT);
    }
}

// out[128][1000] = h(bf16)[128][1024] @ w[1024][1000] + b
__global__ __launch_bounds__(256) void proj_kernel(
    const unsigned short* __restrict__ hb, const float* __restrict__ w,
    const float* __restrict__ bias, float* __restrict__ out)
{
    int cidx = blockIdx.x * 256 + threadIdx.x;  // 0..1023
    int bg   = blockIdx.y;                      // 0..7 -> 16 rows each
    bool valid = cidx < 1000;
    float acc[16];
    #pragma unroll
    for (int i = 0; i < 16; ++i) acc[i] = 0.f;

    for (int k = 0; k < H; k += 4) {
        float w0 = 0.f, w1 = 0.f, w2 = 0.f, w3 = 0.f;
        if (valid) {
            w0 = w[(size_t)(k + 0) * 1000 + cidx];
            w1 = w[(size_t)(k + 1) * 1000 + cidx];
            w2 = w[(size_t)(k + 2) * 1000 + cidx];
            w3 = w[(size_t)(k + 3) * 1000 + cidx];
        }
        #pragma unroll
        for (int i = 0; i < 16; ++i) {
            ushort4 hv = *(const ushort4*)&hb[(size_t)(bg * 16 + i) * H + k];
            acc[i] += bf2f(hv.x) * w0 + bf2f(hv.y) * w1
                    + bf2f(hv.z) * w2 + bf2f(hv.w) * w3;
        }
    }
    if (valid) {
        #pragma unroll
        for (int i = 0; i < 16; ++i)
            out[(size_t)(bg * 16 + i) * 1000 + cidx] = acc[i] + bias[cidx];
    }
}

extern "C" void kernel_launch(void* const* d_in, const int* in_sizes, int n_in,
                              void* d_out, int out_size, void* d_ws, size_t ws_size,
                              hipStream_t stream) {
    const float* x  = (const float*)d_in[0];  // [B,T,D]
    const float* Wk = (const float*)d_in[1];  // [D+H, 4H]
    const float* bk = (const float*)d_in[2];  // [4H]
    const float* w  = (const float*)d_in[3];  // [H, C]
    const float* b  = (const float*)d_in[4];  // [C]
    float* out = (float*)d_out;               // [B, C]

    char* p = (char*)d_ws;
    unsigned short* xb = (unsigned short*)p;  p += (size_t)B * T * D * 2;   // 33.55 MB
    unsigned short* Wp = (unsigned short*)p;  p += (size_t)N4 * KTOT * 2;   // 12.58 MB
    unsigned short* h0 = (unsigned short*)p;  p += (size_t)B * H * 2;
    unsigned short* h1 = (unsigned short*)p;  p += (size_t)B * H * 2;
    unsigned int*   fl = (unsigned int*)p;    p += (size_t)T * 4 * 64 * 4;  // 256 KB

    // flags must start zeroed (ws re-poisoned 0xAA before every timed call).
    // h0/h1 need no init: t=0 skips the h-read entirely.
    hipMemsetAsync(fl, 0, (size_t)T * 4 * 64 * 4, stream);

    convert_x<<<dim3(T * B / 16), dim3(256), 0, stream>>>(x, xb);
    convert_W<<<dim3(N4 / 32, KTOT / 32), dim3(256), 0, stream>>>(Wk, Wp);

    lstm_persist<<<dim3(256), dim3(256), 0, stream>>>(xb, Wp, bk, h0, h1, fl);

    // t=255 (odd) wrote h0 -> final hidden state in h0
    proj_kernel<<<dim3(4, 8), dim3(256), 0, stream>>>(h0, w, b, out);
}